// Round 1
// baseline (175.116 us; speedup 1.0000x reference)
//
#include <hip/hip_runtime.h>
#include <hip/hip_fp16.h>

constexpr int S_LEN  = 2048;
constexpr int HID    = 1024;
constexpr int HEADS  = 16;
constexpr int HDIM   = 64;
constexpr int BATCH  = 2;
constexpr int BH     = BATCH * HEADS;          // 32
constexpr int M_ROWS = BATCH * S_LEN;          // 4096

typedef _Float16 half8  __attribute__((ext_vector_type(8)));
typedef _Float16 half4v __attribute__((ext_vector_type(4)));
typedef _Float16 half2v __attribute__((ext_vector_type(2)));
typedef float    f32x4  __attribute__((ext_vector_type(4)));
typedef float    f32x16 __attribute__((ext_vector_type(16)));

constexpr float EXP2_OFF = -11.541560327111707f;   // -8*log2(e)
constexpr float Q_SCALE  = 0.18033688011112042f;   // 0.125*log2(e)

// ---------------------------------------------------------------------------
// Kernel 0: fp32 -> fp16 convert for X, Wq, Wk, Wv; mask -> fp32 exp2-bias.
// ---------------------------------------------------------------------------
__global__ __launch_bounds__(256) void cvt_kernel(
    const float* __restrict__ X,  const float* __restrict__ Wq,
    const float* __restrict__ Wk, const float* __restrict__ Wv,
    const int* __restrict__ mask,
    _Float16* __restrict__ Xh,  _Float16* __restrict__ Wqh,
    _Float16* __restrict__ Wkh, _Float16* __restrict__ Wvh,
    float* __restrict__ maskF)
{
    const int blk = blockIdx.x;
    if (blk >= 3584) {                       // mask: 2 blocks x 2048 elements
        const int loc = blk - 3584;
        const size_t e = ((size_t)loc * 256 + threadIdx.x) * 8;
        #pragma unroll
        for (int i = 0; i < 8; ++i)
            maskF[e + i] = mask[e + i] ? EXP2_OFF : -1.0e30f;
        return;
    }
    const float* src; _Float16* dst; int loc;
    if (blk < 2048)      { src = X;  dst = Xh;  loc = blk; }
    else if (blk < 2560) { src = Wq; dst = Wqh; loc = blk - 2048; }
    else if (blk < 3072) { src = Wk; dst = Wkh; loc = blk - 2560; }
    else                 { src = Wv; dst = Wvh; loc = blk - 3072; }
    const size_t e = ((size_t)loc * 256 + threadIdx.x) * 8;
    float4 a = *reinterpret_cast<const float4*>(&src[e]);
    float4 b = *reinterpret_cast<const float4*>(&src[e + 4]);
    half8 h = { (_Float16)a.x, (_Float16)a.y, (_Float16)a.z, (_Float16)a.w,
                (_Float16)b.x, (_Float16)b.y, (_Float16)b.z, (_Float16)b.w };
    *reinterpret_cast<half8*>(&dst[e]) = h;
}

// ---------------------------------------------------------------------------
__device__ __forceinline__ void async_cp16(_Float16* lds, const _Float16* g) {
    __builtin_amdgcn_global_load_lds(
        (const __attribute__((address_space(1))) void*)g,
        (__attribute__((address_space(3))) void*)lds, 16, 0, 0);
}

// ---------------------------------------------------------------------------
// Kernel A: QKV projection (unchanged this round).
// ---------------------------------------------------------------------------
__global__ __launch_bounds__(256) void qkv_proj_kernel(
    const _Float16* __restrict__ Xh,
    const _Float16* __restrict__ Wqh, const _Float16* __restrict__ Wkh,
    const _Float16* __restrict__ Wvh,
    const float* __restrict__ bq, const float* __restrict__ bk,
    const float* __restrict__ bv,
    _Float16* __restrict__ Qo, _Float16* __restrict__ Ko,
    _Float16* __restrict__ Vt)
{
    const int mode = blockIdx.z;
    const _Float16* W    = (mode == 0) ? Wqh : (mode == 1) ? Wkh : Wvh;
    const float*    bias = (mode == 0) ? bq  : (mode == 1) ? bk  : bv;

    const int m0 = blockIdx.x * 128, n0 = blockIdx.y * 128;
    const int tid = threadIdx.x, wave = tid >> 6, lane = tid & 63;
    const int l31 = lane & 31, kg = lane >> 5;      // kg: k-half group (0/1)

    __shared__ _Float16 SMEM[18432];

    f32x16 acc[2][2];
    #pragma unroll
    for (int mt = 0; mt < 2; ++mt)
        #pragma unroll
        for (int nt = 0; nt < 2; ++nt)
            #pragma unroll
            for (int i = 0; i < 16; ++i) acc[mt][nt][i] = 0.f;

    const int wm = (wave & 1) * 64, wn = (wave >> 1) * 64;

    const int srow = tid >> 2, spos = tid & 3;
    auto stage = [&](int k0, int b) {
        _Float16* Asb = SMEM + b * 8192;
        _Float16* Bsb = Asb + 4096;
        #pragma unroll
        for (int j = 0; j < 2; ++j) {
            const int row = srow + j * 64;
            const int sch = spos ^ (row & 3);
            async_cp16(&Asb[j * 2048 + tid * 8],
                       &Xh[(size_t)(m0 + row) * HID + k0 + sch * 8]);
            async_cp16(&Bsb[j * 2048 + tid * 8],
                       &W [(size_t)(n0 + row) * HID + k0 + sch * 8]);
        }
    };

    stage(0, 0);
    int buf = 0;

    for (int k0 = 0; k0 < HID; k0 += 32) {
        __syncthreads();
        if (k0 + 32 < HID) stage(k0 + 32, buf ^ 1);
        _Float16* Asb = SMEM + buf * 8192;
        _Float16* Bsb = Asb + 4096;

        #pragma unroll
        for (int c = 0; c < 2; ++c) {               // two k-16 chunks
            const int k8 = c * 2 + kg;              // 16B chunk idx (0..3)
            half8 af[2], bf[2];
            #pragma unroll
            for (int mt = 0; mt < 2; ++mt) {
                const int row = wm + mt * 32 + l31;
                af[mt] = *reinterpret_cast<const half8*>(
                    &Asb[row * 32 + ((k8 ^ (row & 3)) * 8)]);
            }
            #pragma unroll
            for (int nt = 0; nt < 2; ++nt) {
                const int row = wn + nt * 32 + l31;
                bf[nt] = *reinterpret_cast<const half8*>(
                    &Bsb[row * 32 + ((k8 ^ (row & 3)) * 8)]);
            }
            #pragma unroll
            for (int mt = 0; mt < 2; ++mt)
                #pragma unroll
                for (int nt = 0; nt < 2; ++nt)
                    acc[mt][nt] = __builtin_amdgcn_mfma_f32_32x32x16_f16(
                        af[mt], bf[nt], acc[mt][nt], 0, 0, 0);
        }
        buf ^= 1;
    }
    __syncthreads();                       // staging LDS dead -> reuse for T

    _Float16* T = SMEM + wave * 4608;      // wave-private [64][72]

    const int nn  = n0 + wn;               // 64-aligned -> single head
    const int hh  = nn >> 6;
    const int mm  = m0 + wm;               // 64-aligned -> single batch
    const int bb  = mm >> 11;
    const int bhv = bb * HEADS + hh;
    const int s0  = mm & 2047;
    const int rowg = lane >> 3, chunk = lane & 7;   // store-phase mapping

    if (mode < 2) {
        _Float16* Out = (mode == 0) ? Qo : Ko;
        #pragma unroll
        for (int nt = 0; nt < 2; ++nt) {
            const int col = nt * 32 + l31;
            float bias_n = bias[nn + col];
            #pragma unroll
            for (int mt = 0; mt < 2; ++mt)
                #pragma unroll
                for (int r = 0; r < 16; ++r) {
                    const int row_l = (r & 3) + 8 * (r >> 2) + 4 * kg;
                    float v = acc[mt][nt][r] + bias_n;
                    if (mode == 0) v *= Q_SCALE;
                    T[(mt * 32 + row_l) * 72 + col] = (_Float16)v;
                }
        }
        asm volatile("s_waitcnt lgkmcnt(0)" ::: "memory");   // wave-private
        #pragma unroll
        for (int j = 0; j < 8; ++j) {
            const int sr = j * 8 + rowg;
            half8 v = *reinterpret_cast<const half8*>(&T[sr * 72 + chunk * 8]);
            *reinterpret_cast<half8*>(
                &Out[((size_t)bhv * S_LEN + s0 + sr) * HDIM + chunk * 8]) = v;
        }
    } else {
        #pragma unroll
        for (int nt = 0; nt < 2; ++nt) {
            const int col = nt * 32 + l31;
            const float bias_n = bias[nn + col];
            #pragma unroll
            for (int mt = 0; mt < 2; ++mt)
                #pragma unroll
                for (int rg = 0; rg < 4; ++rg) {
                    half4v t = { (_Float16)(acc[mt][nt][rg * 4 + 0] + bias_n),
                                 (_Float16)(acc[mt][nt][rg * 4 + 1] + bias_n),
                                 (_Float16)(acc[mt][nt][rg * 4 + 2] + bias_n),
                                 (_Float16)(acc[mt][nt][rg * 4 + 3] + bias_n) };
                    const int s_off = mt * 32 + 8 * rg + 4 * kg;
                    *reinterpret_cast<half4v*>(&T[col * 72 + s_off]) = t;
                }
        }
        asm volatile("s_waitcnt lgkmcnt(0)" ::: "memory");   // wave-private
        #pragma unroll
        for (int j = 0; j < 8; ++j) {
            const int dr = j * 8 + rowg;
            half8 v = *reinterpret_cast<const half8*>(&T[dr * 72 + chunk * 8]);
            *reinterpret_cast<half8*>(
                &Vt[((size_t)bhv * HDIM + dr) * S_LEN + s0 + chunk * 8]) = v;
        }
    }
}

// ---------------------------------------------------------------------------
// Kernel B: attention, q-reuse rebuild.
//   256 threads (4 waves), each wave owns 32 q-rows (2 groups of 16) ->
//   K/V LDS fragments are read ONCE per wave and reused for both q-groups,
//   cutting per-CU LDS read traffic ~0.64x (the kernel was LDS-BW-bound:
//   MfmaUtil 24 / VALUBusy 39 / HBM 6% / conflicts 0, and the LDS byte
//   arithmetic matched the 58 us duration).
//   Same grid (512 flat, XCD-swizzled, 128 q-rows per block), same
//   XOR-chunk-swizzled K/V staging via global_load_lds, one barrier/iter.
// ---------------------------------------------------------------------------
__global__ __launch_bounds__(256) void attn_kernel(
    const _Float16* __restrict__ Q, const _Float16* __restrict__ K,
    const _Float16* __restrict__ Vt, const float* __restrict__ maskF,
    float* __restrict__ Out)
{
    const int id    = blockIdx.x;
    const int xcd   = id & 7, local = id >> 3;      // local 0..63
    const int bh    = xcd * 4 + (local & 3);        // 4 bh per XCD
    const int qt    = local >> 2;                   // 0..15
    const int b = bh >> 4, h = bh & 15;
    const int tid = threadIdx.x, wave = tid >> 6, lane = tid & 63;
    const int l15 = lane & 15, quad = lane >> 4;

    __shared__ _Float16 Ks[2][64 * 64];             // 8KB x2, swizzled chunks
    __shared__ _Float16 Vs[2][64 * 64];             // 8KB x2, swizzled chunks
    __shared__ _Float16 Ps[4][32][68];              // wave-private P, stride 68

    const _Float16* Qb = Q  + (size_t)bh * S_LEN * HDIM;
    const _Float16* Kb = K  + (size_t)bh * S_LEN * HDIM;
    const _Float16* Vb = Vt + (size_t)bh * HDIM * S_LEN;
    const float*    mb = maskF + b * S_LEN;

    // 32 q-rows per wave: groups g=0,1 at qrow0 + g*16
    const int qrow0 = qt * 128 + wave * 32 + l15;
    half8 qf[2][2];
    #pragma unroll
    for (int g = 0; g < 2; ++g) {
        const size_t qo = (size_t)(qrow0 + g * 16) * HDIM;
        qf[g][0] = *reinterpret_cast<const half8*>(&Qb[qo + quad * 8]);
        qf[g][1] = *reinterpret_cast<const half8*>(&Qb[qo + 32 + quad * 8]);
    }

    f32x4 acc[2][4];
    #pragma unroll
    for (int g = 0; g < 2; ++g)
        #pragma unroll
        for (int mt = 0; mt < 4; ++mt) acc[g][mt] = (f32x4){0.f, 0.f, 0.f, 0.f};
    float den[2] = {0.f, 0.f};

    // staging: 256 lanes x 2 x 16B per tile = full 64x64 fp16 tile.
    // LDS layout identical to before: [row][chunk], chunk XOR-swizzled.
    const int srow_t = tid >> 3;                          // 0..31
    const int sch    = (tid & 7) ^ (srow_t & 7);          // row&7 == srow_t&7
    auto stage = [&](int kb, int buf) {
        #pragma unroll
        for (int j = 0; j < 2; ++j) {
            const int row = srow_t + j * 32;
            async_cp16(&Ks[buf][j * 2048 + tid * 8],
                       &Kb[(size_t)(kb + row) * HDIM + sch * 8]);
            async_cp16(&Vs[buf][j * 2048 + tid * 8],
                       &Vb[(size_t)row * S_LEN + kb + sch * 8]);
        }
    };

    stage(0, 0);
    int buf = 0;
    const int rsw = (l15 & 7);          // read-side swizzle key (row&7)

    for (int kb = 0; kb < S_LEN; kb += 64) {
        __syncthreads();                  // drains staging of `buf` + prev compute
        if (kb + 64 < S_LEN) stage(kb + 64, buf ^ 1);

        float4 m4[4];
        #pragma unroll
        for (int nt = 0; nt < 4; ++nt)
            m4[nt] = *reinterpret_cast<const float4*>(&mb[kb + nt * 16 + quad * 4]);

        // ---- K/V fragments: read ONCE, reused for both q-groups ----
        half8 kf[2][4];
        #pragma unroll
        for (int c = 0; c < 2; ++c)
            #pragma unroll
            for (int nt = 0; nt < 4; ++nt)
                kf[c][nt] = *reinterpret_cast<const half8*>(
                    &Ks[buf][(nt * 16 + l15) * 64 + ((c * 4 + quad) ^ rsw) * 8]);
        half8 vf[2][4];
        #pragma unroll
        for (int c = 0; c < 2; ++c)
            #pragma unroll
            for (int mt = 0; mt < 4; ++mt)
                vf[c][mt] = *reinterpret_cast<const half8*>(
                    &Vs[buf][(mt * 16 + l15) * 64 + ((c * 4 + quad) ^ rsw) * 8]);

        // ---- per q-group: S^T = K.Q'^T ; p = exp2(s+bias) ; stash P ----
        #pragma unroll
        for (int g = 0; g < 2; ++g) {
            f32x4 sc[4];
            #pragma unroll
            for (int nt = 0; nt < 4; ++nt) sc[nt] = (f32x4){0.f, 0.f, 0.f, 0.f};
            #pragma unroll
            for (int c = 0; c < 2; ++c)
                #pragma unroll
                for (int nt = 0; nt < 4; ++nt)
                    sc[nt] = __builtin_amdgcn_mfma_f32_16x16x32_f16(
                        kf[c][nt], qf[g][c], sc[nt], 0, 0, 0);

            #pragma unroll
            for (int nt = 0; nt < 4; ++nt) {
                float p0 = __builtin_amdgcn_exp2f(sc[nt][0] + m4[nt].x);
                float p1 = __builtin_amdgcn_exp2f(sc[nt][1] + m4[nt].y);
                float p2 = __builtin_amdgcn_exp2f(sc[nt][2] + m4[nt].z);
                float p3 = __builtin_amdgcn_exp2f(sc[nt][3] + m4[nt].w);
                den[g] += (p0 + p1) + (p2 + p3);
                half2v lo = __builtin_bit_cast(half2v, __builtin_amdgcn_cvt_pkrtz(p0, p1));
                half2v hi = __builtin_bit_cast(half2v, __builtin_amdgcn_cvt_pkrtz(p2, p3));
                half4v pk = { lo[0], lo[1], hi[0], hi[1] };
                *reinterpret_cast<half4v*>(
                    &Ps[wave][g * 16 + l15][nt * 16 + quad * 4]) = pk;
            }
        }
        asm volatile("s_waitcnt lgkmcnt(0)" ::: "memory");

        // ---- O^T += V^T.P^T for both q-groups (vf reused) ----
        #pragma unroll
        for (int g = 0; g < 2; ++g) {
            #pragma unroll
            for (int c = 0; c < 2; ++c) {
                half4v plo = *reinterpret_cast<const half4v*>(
                    &Ps[wave][g * 16 + l15][c * 32 + quad * 8]);
                half4v phi = *reinterpret_cast<const half4v*>(
                    &Ps[wave][g * 16 + l15][c * 32 + quad * 8 + 4]);
                half8 pf = { plo[0], plo[1], plo[2], plo[3],
                             phi[0], phi[1], phi[2], phi[3] };
                #pragma unroll
                for (int mt = 0; mt < 4; ++mt)
                    acc[g][mt] = __builtin_amdgcn_mfma_f32_16x16x32_f16(
                        vf[c][mt], pf, acc[g][mt], 0, 0, 0);
            }
        }
        buf ^= 1;
    }

    // ---- per group: denominator reduce + epilogue ----
    #pragma unroll
    for (int g = 0; g < 2; ++g) {
        float d = den[g];
        d += __shfl_xor(d, 16, 64);
        d += __shfl_xor(d, 32, 64);
        const float inv = 1.0f / d;
        float* orow = Out + ((size_t)(b * S_LEN + qrow0 + g * 16)) * HID + h * HDIM;
        #pragma unroll
        for (int mt = 0; mt < 4; ++mt) {
            float4 o = { acc[g][mt][0] * inv, acc[g][mt][1] * inv,
                         acc[g][mt][2] * inv, acc[g][mt][3] * inv };
            *reinterpret_cast<float4*>(&orow[mt * 16 + quad * 4]) = o;
        }
    }
}

// ---------------------------------------------------------------------------
extern "C" void kernel_launch(void* const* d_in, const int* in_sizes, int n_in,
                              void* d_out, int out_size, void* d_ws, size_t ws_size,
                              hipStream_t stream) {
    const float* X  = (const float*)d_in[0];
    const int*   mk = (const int*)  d_in[1];
    const float* Wq = (const float*)d_in[2];
    const float* bq = (const float*)d_in[3];
    const float* Wk = (const float*)d_in[4];
    const float* bk = (const float*)d_in[5];
    const float* Wv = (const float*)d_in[6];
    const float* bv = (const float*)d_in[7];
    float* out = (float*)d_out;

    // ws (halves): [Xh 4M][Wqh 1M][Wkh 1M][Wvh 1M][Q 4M][K 4M][Vt 4M][maskF]
    _Float16* Xh  = (_Float16*)d_ws;
    _Float16* Wqh = Xh  + (size_t)M_ROWS * HID;
    _Float16* Wkh = Wqh + (size_t)HID * HID;
    _Float16* Wvh = Wkh + (size_t)HID * HID;
    _Float16* Q   = Wvh + (size_t)HID * HID;
    _Float16* K   = Q   + (size_t)BH * S_LEN * HDIM;
    _Float16* Vt  = K   + (size_t)BH * S_LEN * HDIM;
    float*    maskF = (float*)(Vt + (size_t)BH * S_LEN * HDIM);

    cvt_kernel<<<3586, 256, 0, stream>>>(X, Wq, Wk, Wv, mk, Xh, Wqh, Wkh, Wvh, maskF);

    dim3 gp(M_ROWS / 128, HID / 128, 3);
    qkv_proj_kernel<<<gp, 256, 0, stream>>>(Xh, Wqh, Wkh, Wvh, bq, bk, bv, Q, K, Vt);

    attn_kernel<<<512, 256, 0, stream>>>(Q, K, Vt, maskF, out);
}